// Round 1
// 301.920 us; speedup vs baseline: 1.0125x; 1.0125x over previous
//
#include <hip/hip_runtime.h>
#include <math.h>

using short8 = __attribute__((ext_vector_type(8))) short;
using f32x4  = __attribute__((ext_vector_type(4))) float;
using llong2 = __attribute__((ext_vector_type(2))) long long;
using i32x8  = __attribute__((ext_vector_type(8))) int;

__device__ __forceinline__ ushort f2bf(float f) {
    union { float f; uint u; } c; c.f = f;
    uint u = c.u;
    uint r = (u + 0x7FFFu + ((u >> 16) & 1u)) >> 16;
    return (ushort)r;
}
__device__ __forceinline__ float bf2f(ushort h) {
    union { uint u; float f; } c; c.u = ((uint)h) << 16;
    return c.f;
}
// pack 4 floats -> 4 fp8 e4m3 (OCP on gfx950) in one dword
__device__ __forceinline__ uint pk4_fp8(float a, float b, float c, float d) {
    int v = __builtin_amdgcn_cvt_pk_fp8_f32(a, b, 0, false);
    v = __builtin_amdgcn_cvt_pk_fp8_f32(c, d, v, true);
    return (uint)v;
}
__device__ __forceinline__ unsigned char f2fp8(float x) {
    return (unsigned char)__builtin_amdgcn_cvt_pk_fp8_f32(x, 0.f, 0, false);
}

// async global->LDS, 16 bytes per lane; lds dest = wave-uniform base + lane*16
__device__ __forceinline__ void gload16(const void* g, void* l) {
    __builtin_amdgcn_global_load_lds(
        (const __attribute__((address_space(1))) unsigned int*)g,
        (__attribute__((address_space(3))) unsigned int*)l,
        16, 0, 0);
}

// ---- weight prep: fp32 -> bf16, fold softmax scale into Wq/bq; zero stats --
__global__ __launch_bounds__(256) void prep_weights(
    const float* __restrict__ wq, const float* __restrict__ bq,
    const float* __restrict__ wk, const float* __restrict__ bk,
    const float* __restrict__ wv, const float* __restrict__ wo,
    ushort* __restrict__ Wqk, ushort* __restrict__ Wv, ushort* __restrict__ Wo,
    float* __restrict__ bqk, float* __restrict__ stats, float scale)
{
    int idx = blockIdx.x * 256 + threadIdx.x;
    if (idx < 1024 * 512) {
        float v = (idx < 262144) ? wq[idx] * scale : wk[idx - 262144];
        Wqk[idx] = f2bf(v);
    }
    if (idx < 262144) {
        Wv[idx] = f2bf(wv[idx]);
        Wo[idx] = f2bf(wo[idx]);
    }
    if (idx < 1024) bqk[idx] = (idx < 512) ? bq[idx] * scale : bk[idx - 512];
    if (idx < 256) stats[idx] = 0.f;     // 128 x {sum, sumsq}
}

// ---- GN pass 1: partial sums, 8 blocks per (b,g) group ---------------------
__global__ __launch_bounds__(256) void gn_stats(
    const float* __restrict__ x, float* __restrict__ stats)
{
    int blk = blockIdx.x;               // 1024 = grp*8 + sub
    int grp = blk >> 3, sub = blk & 7;
    const float* xp = x + (size_t)grp * 65536 + sub * 8192;
    int tid = threadIdx.x;

    float s = 0.f, sq = 0.f;
    #pragma unroll
    for (int j = 0; j < 8; ++j) {
        float4 v = *(const float4*)&xp[tid * 4 + j * 1024];
        s  += v.x + v.y + v.z + v.w;
        sq += v.x * v.x + v.y * v.y + v.z * v.z + v.w * v.w;
    }
    #pragma unroll
    for (int off = 32; off; off >>= 1) {
        s  += __shfl_xor(s,  off, 64);
        sq += __shfl_xor(sq, off, 64);
    }
    __shared__ float red[8];
    if ((tid & 63) == 0) { red[(tid >> 6) * 2] = s; red[(tid >> 6) * 2 + 1] = sq; }
    __syncthreads();
    if (tid == 0) {
        atomicAdd(&stats[grp * 2],     red[0] + red[2] + red[4] + red[6]);
        atomicAdd(&stats[grp * 2 + 1], red[1] + red[3] + red[5] + red[7]);
    }
}

// ---- GN pass 2: normalize + transpose one 256-pixel tile -------------------
__global__ __launch_bounds__(256) void gn_apply(
    const float* __restrict__ x, const float* __restrict__ gamma,
    const float* __restrict__ beta, const float* __restrict__ stats,
    ushort* __restrict__ hnt)
{
    int blk = blockIdx.x;               // 2048 = grp*16 + tile
    int grp = blk >> 4, tile = blk & 15;
    int b = grp >> 5, g = grp & 31;
    const float* xp = x + (size_t)grp * 65536;
    int tid = threadIdx.x;

    float mean = stats[grp * 2] * (1.f / 65536.f);
    float var  = stats[grp * 2 + 1] * (1.f / 65536.f) - mean * mean;
    float rstd = rsqrtf(var + 1e-6f);

    int i0 = tile * 256;
    __shared__ ushort ls[16][256];
    #pragma unroll
    for (int ch = 0; ch < 16; ++ch) {
        float a = rstd * gamma[g * 16 + ch];
        float c = beta[g * 16 + ch] - mean * a;
        ls[ch][tid] = f2bf(xp[ch * 4096 + i0 + tid] * a + c);
    }
    __syncthreads();
    ushort t[16];
    #pragma unroll
    for (int ch = 0; ch < 16; ++ch) t[ch] = ls[ch][tid];
    size_t dst = ((size_t)b * 4096 + i0 + tid) * 512 + g * 16;
    *(uint4*)&hnt[dst]     = *(const uint4*)&t[0];
    *(uint4*)&hnt[dst + 8] = *(const uint4*)&t[8];
}

// ---- softmax: bf16 S in -> fp8 (x256) P8 out, natural j order --------------
__global__ __launch_bounds__(256) void softmax_kernel(
    const ushort* __restrict__ S, unsigned char* __restrict__ P8)
{
    size_t row = blockIdx.x;
    const ushort* p = S + row * 4096;
    int tid = threadIdx.x;

    ushort tmp[16];
    *(uint4*)&tmp[0] = *(const uint4*)&p[tid * 16];
    *(uint4*)&tmp[8] = *(const uint4*)&p[tid * 16 + 8];
    float v[16];
    float mx = -1e30f;
    #pragma unroll
    for (int j = 0; j < 16; ++j) { v[j] = bf2f(tmp[j]); mx = fmaxf(mx, v[j]); }
    #pragma unroll
    for (int off = 32; off; off >>= 1) mx = fmaxf(mx, __shfl_xor(mx, off, 64));
    __shared__ float ls[8];
    if ((tid & 63) == 0) ls[tid >> 6] = mx;
    __syncthreads();
    float m4 = fmaxf(fmaxf(ls[0], ls[1]), fmaxf(ls[2], ls[3]));
    float sum = 0.f;
    #pragma unroll
    for (int j = 0; j < 16; ++j) { v[j] = __expf(v[j] - m4); sum += v[j]; }
    #pragma unroll
    for (int off = 32; off; off >>= 1) sum += __shfl_xor(sum, off, 64);
    if ((tid & 63) == 0) ls[4 + (tid >> 6)] = sum;
    __syncthreads();
    // scale by 256 so diffuse probs (~2.4e-4) clear e4m3's subnormal floor;
    // undone via e8m0 2^-8 A-scale in the MX PV MFMA.
    float inv = 256.0f / (ls[4] + ls[5] + ls[6] + ls[7]);
    size_t base = row * 4096 + (size_t)tid * 16;
    uint2 o0, o1;
    o0.x = pk4_fp8(v[0] * inv,  v[1] * inv,  v[2] * inv,  v[3] * inv);
    o0.y = pk4_fp8(v[4] * inv,  v[5] * inv,  v[6] * inv,  v[7] * inv);
    o1.x = pk4_fp8(v[8] * inv,  v[9] * inv,  v[10] * inv, v[11] * inv);
    o1.y = pk4_fp8(v[12] * inv, v[13] * inv, v[14] * inv, v[15] * inv);
    *(uint2*)&P8[base]     = o0;
    *(uint2*)&P8[base + 8] = o1;
}

// ---- NT bf16 MFMA GEMM, 128x128 tile, BK=64 (two 32-k sub-tiles/barrier) ---
// C[m,n] = sum_k A[m,k]*B[n,k]   A: [M][K] lda, B: [N][K] ldb (both K-contig)
// OUT: 0 bf16, 1 fp32 + resid, 2 fp8 natural order, 3 split Q/K fp8 (Q x16).
// BIAS: 0 none, 1 row, 2 col.
template <int BIAS, int OUT>
__global__ __launch_bounds__(256, 4) void gemm_nt(
    const ushort* __restrict__ Ag, const ushort* __restrict__ Bg,
    void* __restrict__ Cv, void* __restrict__ Cv2,
    const float* __restrict__ bias, const float* __restrict__ resid,
    int N, int K, int lda, int ldb,
    long sA, long sB, long sC)
{
    const int bz = blockIdx.z;
    Ag += (size_t)bz * sA;
    Bg += (size_t)bz * sB;

    const int tid  = threadIdx.x;
    const int wave = tid >> 6, lane = tid & 63;
    const int q = lane >> 4, lr = lane & 15;
    const int m0 = blockIdx.x * 128, n0 = blockIdx.y * 128;   // m on X!
    const int wm = (wave >> 1) * 64, wn = (wave & 1) * 64;

    __shared__ __align__(16) ushort As[2][128 * 32];   // 2 x 8 KB
    __shared__ __align__(16) ushort Bs[2][128 * 32];   // 2 x 8 KB

    const int srow = wave * 32 + (lane >> 2);
    const int skc  = (lane & 3) << 3;
    const size_t aoff0 = (size_t)(m0 + srow) * lda + skc;
    const size_t aoff1 = aoff0 + (size_t)16 * lda;
    const size_t boff0 = (size_t)(n0 + srow) * ldb + skc;
    const size_t boff1 = boff0 + (size_t)16 * ldb;
    const int l0 = wave * 1024, l1 = wave * 1024 + 512;   // wave-uniform bases

    f32x4 acc[4][4] = {};

    for (int kb = 0; kb < K; kb += 64) {
        __syncthreads();
        gload16(&Ag[aoff0 + kb],      &As[0][l0]);
        gload16(&Ag[aoff1 + kb],      &As[0][l1]);
        gload16(&Ag[aoff0 + kb + 32], &As[1][l0]);
        gload16(&Ag[aoff1 + kb + 32], &As[1][l1]);
        gload16(&Bg[boff0 + kb],      &Bs[0][l0]);
        gload16(&Bg[boff1 + kb],      &Bs[0][l1]);
        gload16(&Bg[boff0 + kb + 32], &Bs[1][l0]);
        gload16(&Bg[boff1 + kb + 32], &Bs[1][l1]);
        __syncthreads();

        #pragma unroll
        for (int kh = 0; kh < 2; ++kh) {
            short8 af[4], bfr[4];
            #pragma unroll
            for (int mt = 0; mt < 4; ++mt)
                af[mt] = *(const short8*)&As[kh][(wm + mt * 16 + lr) * 32 + q * 8];
            #pragma unroll
            for (int nt = 0; nt < 4; ++nt)
                bfr[nt] = *(const short8*)&Bs[kh][(wn + nt * 16 + lr) * 32 + q * 8];
            #pragma unroll
            for (int mt = 0; mt < 4; ++mt)
                #pragma unroll
                for (int nt = 0; nt < 4; ++nt)
                    acc[mt][nt] = __builtin_amdgcn_mfma_f32_16x16x32_bf16(
                        af[mt], bfr[nt], acc[mt][nt], 0, 0, 0);
        }
    }

    #pragma unroll
    for (int mt = 0; mt < 4; ++mt) {
        int rb = m0 + wm + mt * 16 + q * 4;
        #pragma unroll
        for (int nt = 0; nt < 4; ++nt) {
            int cn = n0 + wn + nt * 16 + lr;
            #pragma unroll
            for (int t = 0; t < 4; ++t) {
                int r = rb + t;
                float v = acc[mt][nt][t];
                if (BIAS == 1) v += bias[r];
                if (BIAS == 2) v += bias[cn];
                if (OUT == 1) {
                    size_t o = (size_t)bz * sC + (size_t)r * N + cn;
                    ((float*)Cv)[o] = v + resid[o];
                } else if (OUT == 2) {
                    ((unsigned char*)Cv)[(size_t)bz * sC + (size_t)r * N + cn] =
                        f2fp8(v);
                } else if (OUT == 3) {
                    // split 1024-wide output: cols [0,512) -> Q8 (x16),
                    // cols [512,1024) -> K8. sC = per-batch elems of each.
                    if (cn < 512)
                        ((unsigned char*)Cv)[(size_t)bz * sC + (size_t)r * 512 + cn]
                            = f2fp8(v * 16.f);
                    else
                        ((unsigned char*)Cv2)[(size_t)bz * sC + (size_t)r * 512 + (cn - 512)]
                            = f2fp8(v);
                } else {
                    size_t o = (size_t)bz * sC + (size_t)r * N + cn;
                    ((ushort*)Cv)[o] = f2bf(v);
                }
            }
        }
    }
}

// ---- scores GEMM, MX-fp8 (K=128 scaled MFMA), 128x128 tile -----------------
// S[i][j] = sum_c Q8[i,c]*2^-4 * K8[j,c].  M=N=4096, K=512 bytes, 4 K-iters.
// LDS rows are 128 B with XOR-swizzled 16B pieces: slot p of row r holds
// global piece p^(r&7), realized by permuting each lane's GLOBAL source
// (dest stays wave-uniform + lane*16). Fragment reads then hit all 32 banks
// at 2 lanes/bank (free).
// Double-buffered prefetch: stage(t+1) issued BEFORE compute(t); one barrier
// per K-iter (its implicit vmcnt(0) drain is what publishes the staged tile).
__global__ __launch_bounds__(256, 2) void gemm_qk(
    const unsigned char* __restrict__ Q8, const unsigned char* __restrict__ K8,
    ushort* __restrict__ S)
{
    const int bz = blockIdx.z;
    const unsigned char* Ag = Q8 + (size_t)bz * 2097152;   // 4096*512
    const unsigned char* Bg = K8 + (size_t)bz * 2097152;

    const int tid  = threadIdx.x;
    const int wave = tid >> 6, lane = tid & 63;
    const int q = lane >> 4, lr = lane & 15;
    const int m0 = blockIdx.x * 128, n0 = blockIdx.y * 128;
    const int wm = (wave >> 1) * 64, wn = (wave & 1) * 64;

    __shared__ __align__(16) unsigned char As[2][128 * 128];   // 2 x 16 KB
    __shared__ __align__(16) unsigned char Bs[2][128 * 128];   // 2 x 16 KB

    // staging: lane i covers local row i>>3, swizzled piece (i&7)^((i>>3)&7)
    const int lrow = lane >> 3;
    const size_t laneoff = (size_t)lrow * 512 + ((lane & 7) ^ (lrow & 7)) * 16;
    const size_t abase = (size_t)(m0 + wave * 32) * 512 + laneoff;
    const size_t bbase = (size_t)(n0 + wave * 32) * 512 + laneoff;
    const int lbase = wave * 32 * 128;      // wave-uniform LDS base

    // fragment read swizzle: row&7 == lr&7 for all tiles (offsets mult of 8)
    const int e0 = (2 * q) ^ (lr & 7), e1 = e0 ^ 1;

    f32x4 acc[4][4] = {};
    const int sA = 0x7B7B7B7B;   // e8m0 2^-4 (undo the x16 in Q8)
    const int sB = 0x7F7F7F7F;   // e8m0 1.0

    auto stage = [&](int kb, int buf) {
        #pragma unroll
        for (int t = 0; t < 4; ++t) {
            gload16(Ag + abase + (size_t)t * 4096 + kb, &As[buf][lbase + t * 1024]);
            gload16(Bg + bbase + (size_t)t * 4096 + kb, &Bs[buf][lbase + t * 1024]);
        }
    };

    stage(0, 0);
    __syncthreads();                         // vmcnt(0) drain: buf0 ready

    for (int it = 0; it < 4; ++it) {
        const int cur = it & 1;
        if (it < 3) stage((it + 1) * 128, cur ^ 1);   // overlap with compute

        i32x8 af[4], bf[4];
        #pragma unroll
        for (int mt = 0; mt < 4; ++mt) {
            int r = wm + mt * 16 + lr;
            union { uint4 v[2]; i32x8 f; } u;
            u.v[0] = *(const uint4*)&As[cur][r * 128 + e0 * 16];
            u.v[1] = *(const uint4*)&As[cur][r * 128 + e1 * 16];
            af[mt] = u.f;
        }
        #pragma unroll
        for (int nt = 0; nt < 4; ++nt) {
            int r = wn + nt * 16 + lr;
            union { uint4 v[2]; i32x8 f; } u;
            u.v[0] = *(const uint4*)&Bs[cur][r * 128 + e0 * 16];
            u.v[1] = *(const uint4*)&Bs[cur][r * 128 + e1 * 16];
            bf[nt] = u.f;
        }
        #pragma unroll
        for (int mt = 0; mt < 4; ++mt)
            #pragma unroll
            for (int nt = 0; nt < 4; ++nt)
                acc[mt][nt] = __builtin_amdgcn_mfma_scale_f32_16x16x128_f8f6f4(
                    af[mt], bf[nt], acc[mt][nt], 0, 0, 0, sA, 0, sB);

        __syncthreads();   // publishes next buf (vmcnt0) + retires cur reads
    }

    #pragma unroll
    for (int mt = 0; mt < 4; ++mt) {
        int rb = m0 + wm + mt * 16 + q * 4;
        #pragma unroll
        for (int nt = 0; nt < 4; ++nt) {
            int cn = n0 + wn + nt * 16 + lr;
            #pragma unroll
            for (int t = 0; t < 4; ++t) {
                size_t o = (size_t)bz * 16777216 + (size_t)(rb + t) * 4096 + cn;
                S[o] = f2bf(acc[mt][nt][t]);
            }
        }
    }
}

// ---- PV GEMM, MX-fp8 (K=128 scaled MFMA), 128x128 tile ---------------------
// Ot[i][c] = sum_j (P8[i,j]*2^-8) * V8[c,j].  M=4096, N=512, K=4096, 32 iters.
// Same structure as gemm_qk: natural j order, XOR-swizzled staging,
// double-buffered prefetch. The 2^-8 A-scale undoes softmax's x256.
__global__ __launch_bounds__(256, 2) void gemm_pv(
    const unsigned char* __restrict__ P8, const unsigned char* __restrict__ V8,
    ushort* __restrict__ Ot)
{
    const int bz = blockIdx.z;
    const unsigned char* Ag = P8 + (size_t)bz * 16777216;   // 4096*4096
    const unsigned char* Bg = V8 + (size_t)bz * 2097152;    // 512*4096

    const int tid  = threadIdx.x;
    const int wave = tid >> 6, lane = tid & 63;
    const int q = lane >> 4, lr = lane & 15;
    const int m0 = blockIdx.x * 128, n0 = blockIdx.y * 128;  // m on X (XCD share)
    const int wm = (wave >> 1) * 64, wn = (wave & 1) * 64;

    __shared__ __align__(16) unsigned char As[2][128 * 128];   // 2 x 16 KB
    __shared__ __align__(16) unsigned char Bs[2][128 * 128];   // 2 x 16 KB

    const int lrow = lane >> 3;
    const size_t laneoff = (size_t)lrow * 4096 + ((lane & 7) ^ (lrow & 7)) * 16;
    const size_t abase = (size_t)(m0 + wave * 32) * 4096 + laneoff;
    const size_t bbase = (size_t)(n0 + wave * 32) * 4096 + laneoff;
    const int lbase = wave * 32 * 128;

    const int e0 = (2 * q) ^ (lr & 7), e1 = e0 ^ 1;

    f32x4 acc[4][4] = {};
    const int sA = 0x77777777;   // e8m0 2^-8 (undo the x256 in P8)
    const int sB = 0x7F7F7F7F;   // e8m0 1.0

    auto stage = [&](int kb, int buf) {
        #pragma unroll
        for (int t = 0; t < 4; ++t) {
            gload16(Ag + abase + (size_t)t * 32768 + kb, &As[buf][lbase + t * 1024]);
            gload16(Bg + bbase + (size_t)t * 32768 + kb, &Bs[buf][lbase + t * 1024]);
        }
    };

    stage(0, 0);
    __syncthreads();

    for (int it = 0; it < 32; ++it) {
        const int cur = it & 1;
        if (it < 31) stage((it + 1) * 128, cur ^ 1);

        i32x8 af[4], bf[4];
        #pragma unroll
        for (int mt = 0; mt < 4; ++mt) {
            int r = wm + mt * 16 + lr;
            union { uint4 v[2]; i32x8 f; } u;
            u.v[0] = *(const uint4*)&As[cur][r * 128 + e0 * 16];
            u.v[1] = *(const uint4*)&As[cur][r * 128 + e1 * 16];
            af[mt] = u.f;
        }
        #pragma unroll
        for (int nt = 0; nt < 4; ++nt) {
            int r = wn + nt * 16 + lr;
            union { uint4 v[2]; i32x8 f; } u;
            u.v[0] = *(const uint4*)&Bs[cur][r * 128 + e0 * 16];
            u.v[1] = *(const uint4*)&Bs[cur][r * 128 + e1 * 16];
            bf[nt] = u.f;
        }
        #pragma unroll
        for (int mt = 0; mt < 4; ++mt)
            #pragma unroll
            for (int nt = 0; nt < 4; ++nt)
                acc[mt][nt] = __builtin_amdgcn_mfma_scale_f32_16x16x128_f8f6f4(
                    af[mt], bf[nt], acc[mt][nt], 0, 0, 0, sA, 0, sB);

        __syncthreads();
    }

    #pragma unroll
    for (int mt = 0; mt < 4; ++mt) {
        int rb = m0 + wm + mt * 16 + q * 4;
        #pragma unroll
        for (int nt = 0; nt < 4; ++nt) {
            int cn = n0 + wn + nt * 16 + lr;
            #pragma unroll
            for (int t = 0; t < 4; ++t) {
                size_t o = (size_t)bz * 2097152 + (size_t)(rb + t) * 512 + cn;
                Ot[o] = f2bf(acc[mt][nt][t]);
            }
        }
    }
}

// ---------------- launch -----------------------------------------------------
extern "C" void kernel_launch(void* const* d_in, const int* in_sizes, int n_in,
                              void* d_out, int out_size, void* d_ws, size_t ws_size,
                              hipStream_t stream)
{
    const float* x   = (const float*)d_in[0];
    const float* gnw = (const float*)d_in[1];
    const float* gnb = (const float*)d_in[2];
    const float* wq  = (const float*)d_in[3];
    const float* bq  = (const float*)d_in[4];
    const float* wk  = (const float*)d_in[5];
    const float* bk  = (const float*)d_in[6];
    const float* wv  = (const float*)d_in[7];
    const float* bv  = (const float*)d_in[8];
    const float* wo  = (const float*)d_in[9];
    const float* bo  = (const float*)d_in[10];
    float* out = (float*)d_out;

    char* ws = (char*)d_ws;
    // ws layout with lifetime overlays (~212 MB):
    //  [0,128M)      S (bf16 scores)  -> dead after softmax; Ot overlays [0,16M)
    //  [128M,144M)   hnt              -> dead after projections
    //  [144M,152M)   Q8, [152M,160M) K8 -> dead after scores
    //  [128M,192M)   P8 (fp8 x256)    -> overlay, written by softmax
    //  [192M,200M)   V8 (fp8)
    //  [200M+..]     weights | bqk | gn stats
    ushort*        S   = (ushort*)(ws);
    ushort*        Ot  = (ushort*)(ws);                       // overlay of S
    ushort*        hnt = (ushort*)(ws + 134217728);
    unsigned char* Q8  = (unsigned char*)(ws + 150994944);
    unsigned char* K8  = (unsigned char*)(ws + 159383552);
    unsigned char* P8  = (unsigned char*)(ws + 134217728);    // overlay
    unsigned char* V8  = (unsigned char*)(ws + 201326592);
    ushort*        Wqk = (ushort*)(ws + 209715200);
    ushort*        Wv  = (ushort*)(ws + 210763776);
    ushort*        Wo  = (ushort*)(ws + 211288064);
    float*         bqk = (float*) (ws + 211812352);
    float*         st  = (float*) (ws + 211816448);           // 128 x {s,sq}

    const float scale = 1.0f / sqrtf(512.0f);
    const long sHW  = 512L * 4096;     // 2 M elems

    prep_weights<<<2048, 256, 0, stream>>>(wq, bq, wk, bk, wv, wo,
                                           Wqk, Wv, Wo, bqk, st, scale);
    gn_stats<<<1024, 256, 0, stream>>>(x, st);
    gn_apply<<<2048, 256, 0, stream>>>(x, gnw, gnb, st, hnt);

    // Q8[i][c]=fp8(16*q), K8[j][c]=fp8(k)  (M=4096, N=1024, K=512), col-bias
    gemm_nt<2, 3><<<dim3(32, 8, 4), 256, 0, stream>>>(
        hnt, Wqk, Q8, K8, bqk, nullptr,
        1024, 512, 512, 512, sHW, 0L, sHW);

    // V8[o][j] = fp8( Wv[o][c] . hn_t[j][c] + bv ), natural j order
    gemm_nt<1, 2><<<dim3(4, 32, 4), 256, 0, stream>>>(
        Wv, hnt, V8, nullptr, bv, nullptr,
        4096, 512, 512, 512, 0L, sHW, sHW);

    // S[i][j] = (Q8*2^-4).K8  (MX fp8 MFMA, K=128/inst, 4 K-iters)
    gemm_qk<<<dim3(32, 32, 4), 256, 0, stream>>>(Q8, K8, S);

    softmax_kernel<<<16384, 256, 0, stream>>>(S, P8);

    // Ot[i][c] = (P8*2^-8) . V8[c][j]  (MX fp8 MFMA, K=128/inst, 32 K-iters)
    gemm_pv<<<dim3(32, 4, 4), 256, 0, stream>>>(P8, V8, Ot);

    // out[o][i] = x + Wo[o][c] . Ot[i][c] + bo  (M=512, N=4096, K=512), fp32
    gemm_nt<1, 1><<<dim3(4, 32, 4), 256, 0, stream>>>(
        Wo, Ot, out, nullptr, bo, x,
        4096, 512, 512, 512, 0L, sHW, sHW);
}

// Round 3
// 285.543 us; speedup vs baseline: 1.0706x; 1.0574x over previous
//
#include <hip/hip_runtime.h>
#include <math.h>

using short8 = __attribute__((ext_vector_type(8))) short;
using f32x4  = __attribute__((ext_vector_type(4))) float;
using llong2 = __attribute__((ext_vector_type(2))) long long;
using i32x8  = __attribute__((ext_vector_type(8))) int;

__device__ __forceinline__ ushort f2bf(float f) {
    union { float f; uint u; } c; c.f = f;
    uint u = c.u;
    uint r = (u + 0x7FFFu + ((u >> 16) & 1u)) >> 16;
    return (ushort)r;
}
__device__ __forceinline__ float bf2f(ushort h) {
    union { uint u; float f; } c; c.u = ((uint)h) << 16;
    return c.f;
}
// pack 4 floats -> 4 fp8 e4m3 (OCP on gfx950) in one dword
__device__ __forceinline__ uint pk4_fp8(float a, float b, float c, float d) {
    int v = __builtin_amdgcn_cvt_pk_fp8_f32(a, b, 0, false);
    v = __builtin_amdgcn_cvt_pk_fp8_f32(c, d, v, true);
    return (uint)v;
}
__device__ __forceinline__ unsigned char f2fp8(float x) {
    return (unsigned char)__builtin_amdgcn_cvt_pk_fp8_f32(x, 0.f, 0, false);
}

// async global->LDS, 16 bytes per lane; lds dest = wave-uniform base + lane*16
__device__ __forceinline__ void gload16(const void* g, void* l) {
    __builtin_amdgcn_global_load_lds(
        (const __attribute__((address_space(1))) unsigned int*)g,
        (__attribute__((address_space(3))) unsigned int*)l,
        16, 0, 0);
}

// ---- weight prep: fp32 -> bf16, fold softmax scale into Wq/bq; zero stats --
__global__ __launch_bounds__(256) void prep_weights(
    const float* __restrict__ wq, const float* __restrict__ bq,
    const float* __restrict__ wk, const float* __restrict__ bk,
    const float* __restrict__ wv, const float* __restrict__ wo,
    ushort* __restrict__ Wqk, ushort* __restrict__ Wv, ushort* __restrict__ Wo,
    float* __restrict__ bqk, float* __restrict__ stats, float scale)
{
    int idx = blockIdx.x * 256 + threadIdx.x;
    if (idx < 1024 * 512) {
        float v = (idx < 262144) ? wq[idx] * scale : wk[idx - 262144];
        Wqk[idx] = f2bf(v);
    }
    if (idx < 262144) {
        Wv[idx] = f2bf(wv[idx]);
        Wo[idx] = f2bf(wo[idx]);
    }
    if (idx < 1024) bqk[idx] = (idx < 512) ? bq[idx] * scale : bk[idx - 512];
    if (idx < 256) stats[idx] = 0.f;     // 128 x {sum, sumsq}
}

// ---- GN pass 1: partial sums, 8 blocks per (b,g) group ---------------------
__global__ __launch_bounds__(256) void gn_stats(
    const float* __restrict__ x, float* __restrict__ stats)
{
    int blk = blockIdx.x;               // 1024 = grp*8 + sub
    int grp = blk >> 3, sub = blk & 7;
    const float* xp = x + (size_t)grp * 65536 + sub * 8192;
    int tid = threadIdx.x;

    float s = 0.f, sq = 0.f;
    #pragma unroll
    for (int j = 0; j < 8; ++j) {
        float4 v = *(const float4*)&xp[tid * 4 + j * 1024];
        s  += v.x + v.y + v.z + v.w;
        sq += v.x * v.x + v.y * v.y + v.z * v.z + v.w * v.w;
    }
    #pragma unroll
    for (int off = 32; off; off >>= 1) {
        s  += __shfl_xor(s,  off, 64);
        sq += __shfl_xor(sq, off, 64);
    }
    __shared__ float red[8];
    if ((tid & 63) == 0) { red[(tid >> 6) * 2] = s; red[(tid >> 6) * 2 + 1] = sq; }
    __syncthreads();
    if (tid == 0) {
        atomicAdd(&stats[grp * 2],     red[0] + red[2] + red[4] + red[6]);
        atomicAdd(&stats[grp * 2 + 1], red[1] + red[3] + red[5] + red[7]);
    }
}

// ---- GN pass 2: normalize + transpose one 256-pixel tile -------------------
__global__ __launch_bounds__(256) void gn_apply(
    const float* __restrict__ x, const float* __restrict__ gamma,
    const float* __restrict__ beta, const float* __restrict__ stats,
    ushort* __restrict__ hnt)
{
    int blk = blockIdx.x;               // 2048 = grp*16 + tile
    int grp = blk >> 4, tile = blk & 15;
    int b = grp >> 5, g = grp & 31;
    const float* xp = x + (size_t)grp * 65536;
    int tid = threadIdx.x;

    float mean = stats[grp * 2] * (1.f / 65536.f);
    float var  = stats[grp * 2 + 1] * (1.f / 65536.f) - mean * mean;
    float rstd = rsqrtf(var + 1e-6f);

    int i0 = tile * 256;
    __shared__ ushort ls[16][256];
    #pragma unroll
    for (int ch = 0; ch < 16; ++ch) {
        float a = rstd * gamma[g * 16 + ch];
        float c = beta[g * 16 + ch] - mean * a;
        ls[ch][tid] = f2bf(xp[ch * 4096 + i0 + tid] * a + c);
    }
    __syncthreads();
    ushort t[16];
    #pragma unroll
    for (int ch = 0; ch < 16; ++ch) t[ch] = ls[ch][tid];
    size_t dst = ((size_t)b * 4096 + i0 + tid) * 512 + g * 16;
    *(uint4*)&hnt[dst]     = *(const uint4*)&t[0];
    *(uint4*)&hnt[dst + 8] = *(const uint4*)&t[8];
}

// ---- softmax: bf16 S in -> fp8 (x256) P8 out, natural j order --------------
__global__ __launch_bounds__(256) void softmax_kernel(
    const ushort* __restrict__ S, unsigned char* __restrict__ P8)
{
    size_t row = blockIdx.x;
    const ushort* p = S + row * 4096;
    int tid = threadIdx.x;

    ushort tmp[16];
    *(uint4*)&tmp[0] = *(const uint4*)&p[tid * 16];
    *(uint4*)&tmp[8] = *(const uint4*)&p[tid * 16 + 8];
    float v[16];
    float mx = -1e30f;
    #pragma unroll
    for (int j = 0; j < 16; ++j) { v[j] = bf2f(tmp[j]); mx = fmaxf(mx, v[j]); }
    #pragma unroll
    for (int off = 32; off; off >>= 1) mx = fmaxf(mx, __shfl_xor(mx, off, 64));
    __shared__ float ls[8];
    if ((tid & 63) == 0) ls[tid >> 6] = mx;
    __syncthreads();
    float m4 = fmaxf(fmaxf(ls[0], ls[1]), fmaxf(ls[2], ls[3]));
    float sum = 0.f;
    #pragma unroll
    for (int j = 0; j < 16; ++j) { v[j] = __expf(v[j] - m4); sum += v[j]; }
    #pragma unroll
    for (int off = 32; off; off >>= 1) sum += __shfl_xor(sum, off, 64);
    if ((tid & 63) == 0) ls[4 + (tid >> 6)] = sum;
    __syncthreads();
    // scale by 256 so diffuse probs (~2.4e-4) clear e4m3's subnormal floor;
    // undone via e8m0 2^-8 A-scale in the MX PV MFMA.
    float inv = 256.0f / (ls[4] + ls[5] + ls[6] + ls[7]);
    size_t base = row * 4096 + (size_t)tid * 16;
    uint2 o0, o1;
    o0.x = pk4_fp8(v[0] * inv,  v[1] * inv,  v[2] * inv,  v[3] * inv);
    o0.y = pk4_fp8(v[4] * inv,  v[5] * inv,  v[6] * inv,  v[7] * inv);
    o1.x = pk4_fp8(v[8] * inv,  v[9] * inv,  v[10] * inv, v[11] * inv);
    o1.y = pk4_fp8(v[12] * inv, v[13] * inv, v[14] * inv, v[15] * inv);
    *(uint2*)&P8[base]     = o0;
    *(uint2*)&P8[base + 8] = o1;
}

// ---- NT bf16 MFMA GEMM, 128x128 tile, BK=64 (two 32-k sub-tiles/barrier) ---
// C[m,n] = sum_k A[m,k]*B[n,k]   A: [M][K] lda, B: [N][K] ldb (both K-contig)
// OUT: 0 bf16, 1 fp32 + resid, 2 fp8 natural order, 3 split Q/K fp8 (Q x16).
// BIAS: 0 none, 1 row, 2 col.
// fp8 outputs (OUT=2/3) go through an LDS-staged coalesced epilogue:
// direct 1-byte stores would emit 16B HBM segments.
template <int BIAS, int OUT>
__global__ __launch_bounds__(256, 4) void gemm_nt(
    const ushort* __restrict__ Ag, const ushort* __restrict__ Bg,
    void* __restrict__ Cv, void* __restrict__ Cv2,
    const float* __restrict__ bias, const float* __restrict__ resid,
    int N, int K, int lda, int ldb,
    long sA, long sB, long sC)
{
    const int bz = blockIdx.z;
    Ag += (size_t)bz * sA;
    Bg += (size_t)bz * sB;

    const int tid  = threadIdx.x;
    const int wave = tid >> 6, lane = tid & 63;
    const int q = lane >> 4, lr = lane & 15;
    const int m0 = blockIdx.x * 128, n0 = blockIdx.y * 128;   // m on X!
    const int wm = (wave >> 1) * 64, wn = (wave & 1) * 64;

    __shared__ __align__(16) ushort As[2][128 * 32];   // 2 x 8 KB
    __shared__ __align__(16) ushort Bs[2][128 * 32];   // 2 x 8 KB

    const int srow = wave * 32 + (lane >> 2);
    const int skc  = (lane & 3) << 3;
    const size_t aoff0 = (size_t)(m0 + srow) * lda + skc;
    const size_t aoff1 = aoff0 + (size_t)16 * lda;
    const size_t boff0 = (size_t)(n0 + srow) * ldb + skc;
    const size_t boff1 = boff0 + (size_t)16 * ldb;
    const int l0 = wave * 1024, l1 = wave * 1024 + 512;   // wave-uniform bases

    f32x4 acc[4][4] = {};

    for (int kb = 0; kb < K; kb += 64) {
        __syncthreads();
        gload16(&Ag[aoff0 + kb],      &As[0][l0]);
        gload16(&Ag[aoff1 + kb],      &As[0][l1]);
        gload16(&Ag[aoff0 + kb + 32], &As[1][l0]);
        gload16(&Ag[aoff1 + kb + 32], &As[1][l1]);
        gload16(&Bg[boff0 + kb],      &Bs[0][l0]);
        gload16(&Bg[boff1 + kb],      &Bs[0][l1]);
        gload16(&Bg[boff0 + kb + 32], &Bs[1][l0]);
        gload16(&Bg[boff1 + kb + 32], &Bs[1][l1]);
        __syncthreads();

        #pragma unroll
        for (int kh = 0; kh < 2; ++kh) {
            short8 af[4], bfr[4];
            #pragma unroll
            for (int mt = 0; mt < 4; ++mt)
                af[mt] = *(const short8*)&As[kh][(wm + mt * 16 + lr) * 32 + q * 8];
            #pragma unroll
            for (int nt = 0; nt < 4; ++nt)
                bfr[nt] = *(const short8*)&Bs[kh][(wn + nt * 16 + lr) * 32 + q * 8];
            #pragma unroll
            for (int mt = 0; mt < 4; ++mt)
                #pragma unroll
                for (int nt = 0; nt < 4; ++nt)
                    acc[mt][nt] = __builtin_amdgcn_mfma_f32_16x16x32_bf16(
                        af[mt], bfr[nt], acc[mt][nt], 0, 0, 0);
        }
    }

    if (OUT == 2 || OUT == 3) {
        // ---- LDS-staged fp8 epilogue: 128x128 bytes, XOR 16B-chunk swizzle
        __syncthreads();                      // loop reads of As/Bs done
        unsigned char* C8 = (unsigned char*)&As[0][0];   // 16 KB
        #pragma unroll
        for (int mt = 0; mt < 4; ++mt) {
            #pragma unroll
            for (int nt = 0; nt < 4; ++nt) {
                int col = wn + nt * 16 + lr;
                #pragma unroll
                for (int t = 0; t < 4; ++t) {
                    int row = wm + mt * 16 + q * 4 + t;
                    float v = acc[mt][nt][t];
                    if (BIAS == 1) v += bias[m0 + row];
                    if (BIAS == 2) v += bias[n0 + col];
                    if (OUT == 3 && n0 < 512) v *= 16.f;
                    C8[row * 128 + ((((col >> 4) ^ (row & 7)) << 4) | (col & 15))]
                        = f2fp8(v);
                }
            }
        }
        __syncthreads();
        const int er = tid >> 3, eck = tid & 7;    // 32 rows/pass x 8 chunks
        #pragma unroll
        for (int p = 0; p < 4; ++p) {
            int row = p * 32 + er;
            uint4 v = *(const uint4*)&C8[row * 128 + ((eck ^ (row & 7)) << 4)];
            if (OUT == 2) {
                *(uint4*)&((unsigned char*)Cv)[(size_t)bz * sC
                    + (size_t)(m0 + row) * N + n0 + eck * 16] = v;
            } else {   // OUT == 3
                if (n0 < 512)
                    *(uint4*)&((unsigned char*)Cv)[(size_t)bz * sC
                        + (size_t)(m0 + row) * 512 + n0 + eck * 16] = v;
                else
                    *(uint4*)&((unsigned char*)Cv2)[(size_t)bz * sC
                        + (size_t)(m0 + row) * 512 + (n0 - 512) + eck * 16] = v;
            }
        }
        return;
    }

    #pragma unroll
    for (int mt = 0; mt < 4; ++mt) {
        int rb = m0 + wm + mt * 16 + q * 4;
        #pragma unroll
        for (int nt = 0; nt < 4; ++nt) {
            int cn = n0 + wn + nt * 16 + lr;
            #pragma unroll
            for (int t = 0; t < 4; ++t) {
                int r = rb + t;
                float v = acc[mt][nt][t];
                if (BIAS == 1) v += bias[r];
                if (BIAS == 2) v += bias[cn];
                if (OUT == 1) {
                    size_t o = (size_t)bz * sC + (size_t)r * N + cn;
                    ((float*)Cv)[o] = v + resid[o];
                } else {
                    size_t o = (size_t)bz * sC + (size_t)r * N + cn;
                    ((ushort*)Cv)[o] = f2bf(v);
                }
            }
        }
    }
}

// ---- scores GEMM, MX-fp8 (K=128 scaled MFMA), 128x128 tile -----------------
// S[i][j] = sum_c Q8[i,c]*2^-4 * K8[j,c].  M=N=4096, K=512 bytes, 4 K-iters.
// LDS rows are 128 B with XOR-swizzled 16B pieces: slot p of row r holds
// global piece p^(r&7), realized by permuting each lane's GLOBAL source
// (dest stays wave-uniform + lane*16). Fragment reads then hit all 32 banks
// at 2 lanes/bank (free). Single-buffered 2-barrier loop (the dbuf variant
// measured SLOWER: wave-level overlap across resident blocks already hides
// staging; dbuf only cost occupancy).
// Epilogue stages the bf16 C-tile in LDS (reusing As+Bs) so S is written as
// 256B-contiguous dwordx4 segments instead of scattered 2B stores.
__global__ __launch_bounds__(256, 2) void gemm_qk(
    const unsigned char* __restrict__ Q8, const unsigned char* __restrict__ K8,
    ushort* __restrict__ S)
{
    const int bz = blockIdx.z;
    const unsigned char* Ag = Q8 + (size_t)bz * 2097152;   // 4096*512
    const unsigned char* Bg = K8 + (size_t)bz * 2097152;

    const int tid  = threadIdx.x;
    const int wave = tid >> 6, lane = tid & 63;
    const int q = lane >> 4, lr = lane & 15;
    const int m0 = blockIdx.x * 128, n0 = blockIdx.y * 128;
    const int wm = (wave >> 1) * 64, wn = (wave & 1) * 64;

    __shared__ __align__(16) unsigned char smem[32768];
    unsigned char* As = smem;            // 16 KB
    unsigned char* Bs = smem + 16384;    // 16 KB
    ushort* Cs = (ushort*)smem;          // epilogue alias, 32 KB

    // staging: lane i covers local row i>>3, swizzled piece (i&7)^((i>>3)&7)
    const int lrow = lane >> 3;
    const size_t laneoff = (size_t)lrow * 512 + ((lane & 7) ^ (lrow & 7)) * 16;
    const size_t abase = (size_t)(m0 + wave * 32) * 512 + laneoff;
    const size_t bbase = (size_t)(n0 + wave * 32) * 512 + laneoff;
    unsigned char* lA = As + wave * 32 * 128;   // wave-uniform
    unsigned char* lB = Bs + wave * 32 * 128;

    // fragment read swizzle: row&7 == lr&7 for all tiles (offsets mult of 8)
    const int e0 = (2 * q) ^ (lr & 7), e1 = e0 ^ 1;

    f32x4 acc[4][4] = {};
    const int sA = 0x7B7B7B7B;   // e8m0 2^-4 (undo the x16 in Q8)
    const int sB = 0x7F7F7F7F;   // e8m0 1.0

    for (int kb = 0; kb < 512; kb += 128) {
        __syncthreads();
        #pragma unroll
        for (int t = 0; t < 4; ++t) {
            gload16(Ag + abase + (size_t)t * 4096 + kb, lA + t * 1024);
            gload16(Bg + bbase + (size_t)t * 4096 + kb, lB + t * 1024);
        }
        __syncthreads();

        i32x8 af[4], bf[4];
        #pragma unroll
        for (int mt = 0; mt < 4; ++mt) {
            int r = wm + mt * 16 + lr;
            union { uint4 v[2]; i32x8 f; } u;
            u.v[0] = *(const uint4*)&As[r * 128 + e0 * 16];
            u.v[1] = *(const uint4*)&As[r * 128 + e1 * 16];
            af[mt] = u.f;
        }
        #pragma unroll
        for (int nt = 0; nt < 4; ++nt) {
            int r = wn + nt * 16 + lr;
            union { uint4 v[2]; i32x8 f; } u;
            u.v[0] = *(const uint4*)&Bs[r * 128 + e0 * 16];
            u.v[1] = *(const uint4*)&Bs[r * 128 + e1 * 16];
            bf[nt] = u.f;
        }
        #pragma unroll
        for (int mt = 0; mt < 4; ++mt)
            #pragma unroll
            for (int nt = 0; nt < 4; ++nt)
                acc[mt][nt] = __builtin_amdgcn_mfma_scale_f32_16x16x128_f8f6f4(
                    af[mt], bf[nt], acc[mt][nt], 0, 0, 0, sA, 0, sB);
    }

    // ---- coalesced epilogue via LDS (bf16 tile, XOR 16B-chunk swizzle) -----
    __syncthreads();
    #pragma unroll
    for (int mt = 0; mt < 4; ++mt) {
        #pragma unroll
        for (int nt = 0; nt < 4; ++nt) {
            int col = wn + nt * 16 + lr;
            #pragma unroll
            for (int t = 0; t < 4; ++t) {
                int row = wm + mt * 16 + q * 4 + t;
                Cs[row * 128 + ((((col >> 3) ^ (row & 7)) << 3) | (col & 7))]
                    = f2bf(acc[mt][nt][t]);
            }
        }
    }
    __syncthreads();
    const int er = tid >> 4, eck = tid & 15;   // 16 rows/pass x 16 chunks
    ushort* orow = S + (size_t)bz * 16777216 + (size_t)m0 * 4096 + n0;
    #pragma unroll
    for (int p = 0; p < 8; ++p) {
        int row = p * 16 + er;
        uint4 v = *(const uint4*)&Cs[row * 128 + ((eck ^ (row & 7)) << 3)];
        *(uint4*)&orow[(size_t)row * 4096 + eck * 8] = v;
    }
}

// ---- PV GEMM, MX-fp8 (K=128 scaled MFMA), 128x128 tile ---------------------
// Ot[i][c] = sum_j (P8[i,j]*2^-8) * V8[c,j].  M=4096, N=512, K=4096, 32 iters.
// Same structure as gemm_qk: natural j order, XOR-swizzled staging,
// single-buffered 2-barrier loop, LDS-staged coalesced epilogue.
__global__ __launch_bounds__(256, 2) void gemm_pv(
    const unsigned char* __restrict__ P8, const unsigned char* __restrict__ V8,
    ushort* __restrict__ Ot)
{
    const int bz = blockIdx.z;
    const unsigned char* Ag = P8 + (size_t)bz * 16777216;   // 4096*4096
    const unsigned char* Bg = V8 + (size_t)bz * 2097152;    // 512*4096

    const int tid  = threadIdx.x;
    const int wave = tid >> 6, lane = tid & 63;
    const int q = lane >> 4, lr = lane & 15;
    const int m0 = blockIdx.x * 128, n0 = blockIdx.y * 128;  // m on X (XCD share)
    const int wm = (wave >> 1) * 64, wn = (wave & 1) * 64;

    __shared__ __align__(16) unsigned char smem[32768];
    unsigned char* As = smem;            // 16 KB
    unsigned char* Bs = smem + 16384;    // 16 KB
    ushort* Cs = (ushort*)smem;          // epilogue alias, 32 KB

    const int lrow = lane >> 3;
    const size_t laneoff = (size_t)lrow * 4096 + ((lane & 7) ^ (lrow & 7)) * 16;
    const size_t abase = (size_t)(m0 + wave * 32) * 4096 + laneoff;
    const size_t bbase = (size_t)(n0 + wave * 32) * 4096 + laneoff;
    unsigned char* lA = As + wave * 32 * 128;
    unsigned char* lB = Bs + wave * 32 * 128;

    const int e0 = (2 * q) ^ (lr & 7), e1 = e0 ^ 1;

    f32x4 acc[4][4] = {};
    const int sA = 0x77777777;   // e8m0 2^-8 (undo the x256 in P8)
    const int sB = 0x7F7F7F7F;   // e8m0 1.0

    for (int kb = 0; kb < 4096; kb += 128) {
        __syncthreads();
        #pragma unroll
        for (int t = 0; t < 4; ++t) {
            gload16(Ag + abase + (size_t)t * 32768 + kb, lA + t * 1024);
            gload16(Bg + bbase + (size_t)t * 32768 + kb, lB + t * 1024);
        }
        __syncthreads();

        i32x8 af[4], bf[4];
        #pragma unroll
        for (int mt = 0; mt < 4; ++mt) {
            int r = wm + mt * 16 + lr;
            union { uint4 v[2]; i32x8 f; } u;
            u.v[0] = *(const uint4*)&As[r * 128 + e0 * 16];
            u.v[1] = *(const uint4*)&As[r * 128 + e1 * 16];
            af[mt] = u.f;
        }
        #pragma unroll
        for (int nt = 0; nt < 4; ++nt) {
            int r = wn + nt * 16 + lr;
            union { uint4 v[2]; i32x8 f; } u;
            u.v[0] = *(const uint4*)&Bs[r * 128 + e0 * 16];
            u.v[1] = *(const uint4*)&Bs[r * 128 + e1 * 16];
            bf[nt] = u.f;
        }
        #pragma unroll
        for (int mt = 0; mt < 4; ++mt)
            #pragma unroll
            for (int nt = 0; nt < 4; ++nt)
                acc[mt][nt] = __builtin_amdgcn_mfma_scale_f32_16x16x128_f8f6f4(
                    af[mt], bf[nt], acc[mt][nt], 0, 0, 0, sA, 0, sB);
    }

    // ---- coalesced epilogue via LDS ----------------------------------------
    __syncthreads();
    #pragma unroll
    for (int mt = 0; mt < 4; ++mt) {
        #pragma unroll
        for (int nt = 0; nt < 4; ++nt) {
            int col = wn + nt * 16 + lr;
            #pragma unroll
            for (int t = 0; t < 4; ++t) {
                int row = wm + mt * 16 + q * 4 + t;
                Cs[row * 128 + ((((col >> 3) ^ (row & 7)) << 3) | (col & 7))]
                    = f2bf(acc[mt][nt][t]);
            }
        }
    }
    __syncthreads();
    const int er = tid >> 4, eck = tid & 15;
    ushort* orow = Ot + (size_t)bz * 2097152 + (size_t)m0 * 512 + n0;
    #pragma unroll
    for (int p = 0; p < 8; ++p) {
        int row = p * 16 + er;
        uint4 v = *(const uint4*)&Cs[row * 128 + ((eck ^ (row & 7)) << 3)];
        *(uint4*)&orow[(size_t)row * 512 + eck * 8] = v;
    }
}

// ---------------- launch -----------------------------------------------------
extern "C" void kernel_launch(void* const* d_in, const int* in_sizes, int n_in,
                              void* d_out, int out_size, void* d_ws, size_t ws_size,
                              hipStream_t stream)
{
    const float* x   = (const float*)d_in[0];
    const float* gnw = (const float*)d_in[1];
    const float* gnb = (const float*)d_in[2];
    const float* wq  = (const float*)d_in[3];
    const float* bq  = (const float*)d_in[4];
    const float* wk  = (const float*)d_in[5];
    const float* bk  = (const float*)d_in[6];
    const float* wv  = (const float*)d_in[7];
    const float* bv  = (const float*)d_in[8];
    const float* wo  = (const float*)d_in[9];
    const float* bo  = (const float*)d_in[10];
    float* out = (float*)d_out;

    char* ws = (char*)d_ws;
    // ws layout with lifetime overlays (~212 MB):
    //  [0,128M)      S (bf16 scores)  -> dead after softmax; Ot overlays [0,16M)
    //  [128M,144M)   hnt              -> dead after projections
    //  [144M,152M)   Q8, [152M,160M) K8 -> dead after scores
    //  [128M,192M)   P8 (fp8 x256)    -> overlay, written by softmax
    //  [192M,200M)   V8 (fp8)
    //  [200M+..]     weights | bqk | gn stats
    ushort*        S   = (ushort*)(ws);
    ushort*        Ot  = (ushort*)(ws);                       // overlay of S
    ushort*        hnt = (ushort*)(ws + 134217728);
    unsigned char* Q8  = (unsigned char*)(ws + 150994944);
    unsigned char* K8  = (unsigned char*)(ws + 159383552);
    unsigned char* P8  = (unsigned char*)(ws + 134217728);    // overlay
    unsigned char* V8  = (unsigned char*)(ws + 201326592);
    ushort*        Wqk = (ushort*)(ws + 209715200);
    ushort*        Wv  = (ushort*)(ws + 210763776);
    ushort*        Wo  = (ushort*)(ws + 211288064);
    float*         bqk = (float*) (ws + 211812352);
    float*         st  = (float*) (ws + 211816448);           // 128 x {s,sq}

    const float scale = 1.0f / sqrtf(512.0f);
    const long sHW  = 512L * 4096;     // 2 M elems

    prep_weights<<<2048, 256, 0, stream>>>(wq, bq, wk, bk, wv, wo,
                                           Wqk, Wv, Wo, bqk, st, scale);
    gn_stats<<<1024, 256, 0, stream>>>(x, st);
    gn_apply<<<2048, 256, 0, stream>>>(x, gnw, gnb, st, hnt);

    // Q8[i][c]=fp8(16*q), K8[j][c]=fp8(k)  (M=4096, N=1024, K=512), col-bias
    gemm_nt<2, 3><<<dim3(32, 8, 4), 256, 0, stream>>>(
        hnt, Wqk, Q8, K8, bqk, nullptr,
        1024, 512, 512, 512, sHW, 0L, sHW);

    // V8[o][j] = fp8( Wv[o][c] . hn_t[j][c] + bv ), natural j order
    gemm_nt<1, 2><<<dim3(4, 32, 4), 256, 0, stream>>>(
        Wv, hnt, V8, nullptr, bv, nullptr,
        4096, 512, 512, 512, 0L, sHW, sHW);

    // S[i][j] = (Q8*2^-4).K8  (MX fp8 MFMA, K=128/inst, 4 K-iters)
    gemm_qk<<<dim3(32, 32, 4), 256, 0, stream>>>(Q8, K8, S);

    softmax_kernel<<<16384, 256, 0, stream>>>(S, P8);

    // Ot[i][c] = (P8*2^-8) . V8[c][j]  (MX fp8 MFMA, K=128/inst, 32 K-iters)
    gemm_pv<<<dim3(32, 4, 4), 256, 0, stream>>>(P8, V8, Ot);

    // out[o][i] = x + Wo[o][c] . Ot[i][c] + bo  (M=512, N=4096, K=512), fp32
    gemm_nt<1, 1><<<dim3(4, 32, 4), 256, 0, stream>>>(
        Wo, Ot, out, nullptr, bo, x,
        4096, 512, 512, 512, 0L, sHW, sHW);
}